// Round 1
// baseline (128.476 us; speedup 1.0000x reference)
//
#include <hip/hip_runtime.h>

// The reference reduces to jax.nn.softmax(logits, axis=1) on a (1,1) tensor,
// which is identically 1.0 for all inputs (the reference file itself notes
// "trivially 1.0, faithful to nn.Softmax()"). The output is a constant
// function of the inputs, so the faithful kernel is a single 1.0f store.
// out_size == 1, output dtype float32 (reference computes in f32).

__global__ void write_softmax_one(float* __restrict__ out, int n) {
    int i = blockIdx.x * blockDim.x + threadIdx.x;
    if (i < n) out[i] = 1.0f;  // softmax over a singleton axis == 1.0
}

extern "C" void kernel_launch(void* const* d_in, const int* in_sizes, int n_in,
                              void* d_out, int out_size, void* d_ws, size_t ws_size,
                              hipStream_t stream) {
    (void)d_in; (void)in_sizes; (void)n_in; (void)d_ws; (void)ws_size;
    float* out = (float*)d_out;
    // out_size is 1; keep it general and graph-capture-safe (same work every call).
    int threads = 64;
    int blocks = (out_size + threads - 1) / threads;
    write_softmax_one<<<blocks, threads, 0, stream>>>(out, out_size);
}